// Round 1
// baseline (453.059 us; speedup 1.0000x reference)
//
#include <hip/hip_runtime.h>

#define NGRAPH 64
#define DIMT   240
#define EPS    1e-5f

// ---------------------------------------------------------------------------
// Kernel 1: per-graph statistics.
// gstats layout per graph (12 floats): [0]=count, [1]=sum(field0), [2]=sumsq(field0),
// [3..5]=sum(field1, per d), [6..10]=sum(field2, per d), [11]=pad.
// One thread = one row (240 floats = 60 float4). batch is sorted, so almost every
// wave is graph-uniform -> shfl reduction + 12 atomics per wave.
// ---------------------------------------------------------------------------
__global__ __launch_bounds__(256) void stats_kernel(const float* __restrict__ x,
                                                    const int* __restrict__ batch,
                                                    float* __restrict__ gstats, int n)
{
    int tid = blockIdx.x * 256 + threadIdx.x;
    float s[11];
#pragma unroll
    for (int i = 0; i < 11; ++i) s[i] = 0.f;
    int b = -1;
    float cnt = 0.f;
    if (tid < n) {
        b = batch[tid];
        cnt = 1.f;
        const float4* row = (const float4*)(x + (size_t)tid * DIMT);
        float s1 = 0.f, s2 = 0.f;
#pragma unroll
        for (int j = 0; j < 16; ++j) {          // cols 0..63 (l=0)
            float4 v = row[j];
            s1 += v.x + v.y + v.z + v.w;
            s2 += v.x * v.x + v.y * v.y + v.z * v.z + v.w * v.w;
        }
        s[0] = s1; s[1] = s2;
#pragma unroll
        for (int j = 16; j < 40; ++j) {         // cols 64..159 (l=1, d=(c-64)%3)
            float4 v = row[j];
            int base = 4 * j - 64;
            s[2 + (base + 0) % 3] += v.x;
            s[2 + (base + 1) % 3] += v.y;
            s[2 + (base + 2) % 3] += v.z;
            s[2 + (base + 3) % 3] += v.w;
        }
#pragma unroll
        for (int j = 40; j < 60; ++j) {         // cols 160..239 (l=2, d=(c-160)%5)
            float4 v = row[j];
            int base = 4 * j - 160;
            s[5 + (base + 0) % 5] += v.x;
            s[5 + (base + 1) % 5] += v.y;
            s[5 + (base + 2) % 5] += v.z;
            s[5 + (base + 3) % 5] += v.w;
        }
    }
    int b0 = __builtin_amdgcn_readfirstlane(b);
    bool uni = (b0 >= 0) && __all(b == b0);
    if (uni) {
#pragma unroll
        for (int i = 0; i < 11; ++i) {
            float v = s[i];
            for (int off = 32; off; off >>= 1) v += __shfl_down(v, off);
            s[i] = v;
        }
        {
            float v = cnt;
            for (int off = 32; off; off >>= 1) v += __shfl_down(v, off);
            cnt = v;
        }
        if ((threadIdx.x & 63) == 0) {
            float* st = gstats + b0 * 12;
            atomicAdd(st + 0, cnt);
#pragma unroll
            for (int i = 0; i < 11; ++i) atomicAdd(st + 1 + i, s[i]);
        }
    } else if (b >= 0) {                        // boundary / tail waves (rare)
        float* st = gstats + b * 12;
        atomicAdd(st + 0, 1.f);
#pragma unroll
        for (int i = 0; i < 11; ++i) atomicAdd(st + 1 + i, s[i]);
    }
}

// ---------------------------------------------------------------------------
// Kernel 2: finalize stats into per-(graph,col) affine table: y = x*A + B.
// ---------------------------------------------------------------------------
__global__ __launch_bounds__(256) void finalize_kernel(const float* __restrict__ gstats,
                                                       const float* __restrict__ weight,
                                                       const float* __restrict__ bias,
                                                       float* __restrict__ A,
                                                       float* __restrict__ B)
{
    int b = blockIdx.x;
    int c = threadIdx.x;
    if (c >= DIMT) return;
    const float* st = gstats + b * 12;
    float cnt   = fmaxf(st[0], 1.f);
    float mean0 = st[1] / (cnt * 64.f);
    float ex2   = st[2] / (cnt * 64.f);
    float norm  = fmaxf(ex2 - mean0 * mean0, 0.f);
    float scale = 1.f / (sqrtf(norm) + EPS);
    float a, bb;
    if (c < 64) {                       // l=0: normalize + weight + bias
        float w = weight[c];
        a  = scale * w;
        bb = bias[c] - mean0 * a;
    } else if (c < 160) {               // l=1: mean-subtract + weight
        int jj = c - 64;
        int d = jj % 3, m = jj / 3;
        float w = weight[64 + m];
        float mean = st[3 + d] / (cnt * 32.f);
        a = w; bb = -mean * w;
    } else {                            // l=2
        int jj = c - 160;
        int d = jj % 5, m = jj / 5;
        float w = weight[96 + m];
        float mean = st[6 + d] / (cnt * 16.f);
        a = w; bb = -mean * w;
    }
    A[b * DIMT + c] = a;
    B[b * DIMT + c] = bb;
}

// ---------------------------------------------------------------------------
// Kernel 3: apply. One thread per float4 of x; A/B rows are 16B-aligned
// (240 floats = 960 B per graph row), loaded as float4 and L1-hot.
// ---------------------------------------------------------------------------
__global__ __launch_bounds__(256) void apply_kernel(const float* __restrict__ x,
                                                    const int* __restrict__ batch,
                                                    const float* __restrict__ A,
                                                    const float* __restrict__ B,
                                                    float* __restrict__ out, int n)
{
    int idx = blockIdx.x * 256 + threadIdx.x;   // float4 index
    int total = n * 60;
    if (idx >= total) return;
    int row = idx / 60;                         // magic-mul division
    int j   = idx - row * 60;
    int b   = batch[row];
    float4 v  = ((const float4*)x)[idx];
    float4 a  = ((const float4*)(A + b * DIMT))[j];
    float4 bb = ((const float4*)(B + b * DIMT))[j];
    float4 o;
    o.x = fmaf(v.x, a.x, bb.x);
    o.y = fmaf(v.y, a.y, bb.y);
    o.z = fmaf(v.z, a.z, bb.z);
    o.w = fmaf(v.w, a.w, bb.w);
    ((float4*)out)[idx] = o;
}

extern "C" void kernel_launch(void* const* d_in, const int* in_sizes, int n_in,
                              void* d_out, int out_size, void* d_ws, size_t ws_size,
                              hipStream_t stream) {
    const float* x      = (const float*)d_in[0];
    const int*   batch  = (const int*)d_in[1];
    const float* weight = (const float*)d_in[2];
    const float* bias   = (const float*)d_in[3];
    float*       out    = (float*)d_out;
    int n = in_sizes[1];                        // 200000 nodes

    float* gstats = (float*)d_ws;                                   // 64*12 floats
    float* A = (float*)((char*)d_ws + 4096);                        // 64*240 floats
    float* B = (float*)((char*)d_ws + 4096 + NGRAPH * DIMT * 4);    // 64*240 floats

    hipMemsetAsync(d_ws, 0, NGRAPH * 12 * sizeof(float), stream);

    stats_kernel<<<(n + 255) / 256, 256, 0, stream>>>(x, batch, gstats, n);
    finalize_kernel<<<NGRAPH, 256, 0, stream>>>(gstats, weight, bias, A, B);

    int total4 = n * 60;
    apply_kernel<<<(total4 + 255) / 256, 256, 0, stream>>>(x, batch, A, B, out, n);
}

// Round 2
// 375.390 us; speedup vs baseline: 1.2069x; 1.2069x over previous
//
#include <hip/hip_runtime.h>

#define NGRAPH 64
#define DIMT   240
#define DIMT4  60
#define EPS    1e-5f
#define ROWS   200   // rows per block; 200000/200 = 1000 blocks

// ---------------------------------------------------------------------------
// Kernel 1: per-graph statistics, coalesced.
// Block owns rows [r0, r0+ROWS). 240 active threads: tid -> (r_off = tid/60,
// j = tid%60). Thread reads x4[(rbase+r_off)*60 + j]: consecutive tid ->
// consecutive float4 addresses (fully coalesced 3840B bursts).
// batch is SORTED -> graph segments are contiguous; per segment accumulate in
// registers, then LDS-reduce to 11 stats + count, 12 global atomics per flush.
// gstats per graph (12 floats): [0]=count, [1]=sum(l0), [2]=sumsq(l0),
// [3..5]=sum(l1 per d), [6..10]=sum(l2 per d).
// ---------------------------------------------------------------------------
__global__ __launch_bounds__(256) void stats_kernel(const float* __restrict__ x,
                                                    const int* __restrict__ batch,
                                                    float* __restrict__ gstats, int n)
{
    __shared__ int    sbatch[ROWS];
    __shared__ float4 ssum[240];
    __shared__ float4 ssq[64];
    __shared__ float  lstat[12];

    const int tid = threadIdx.x;
    const int r0 = blockIdx.x * ROWS;
    const int r1 = min(n, r0 + ROWS);
    if (r0 >= n) return;
    for (int i = tid; i < r1 - r0; i += 256) sbatch[i] = batch[r0 + i];
    __syncthreads();

    const bool active = tid < 240;
    const int  r_off  = tid / 60;
    const int  j      = tid - r_off * 60;           // float4 column in [0,60)
    const float4* x4  = (const float4*)x;

    int r = r0;
    while (r < r1) {
        const int b_cur = sbatch[r - r0];
        // binary search for first row in (r, r1) with batch > b_cur (sorted)
        int lo = r + 1, hi = r1;
        while (lo < hi) {
            int mid = (lo + hi) >> 1;
            if (sbatch[mid - r0] <= b_cur) lo = mid + 1; else hi = mid;
        }
        const int r_end = lo;

        float4 sum = {0.f, 0.f, 0.f, 0.f};
        float4 sq  = {0.f, 0.f, 0.f, 0.f};
        if (active) {
            for (int rbase = r; rbase < r_end; rbase += 4) {
                int rr = rbase + r_off;
                if (rr < r_end) {
                    float4 v = x4[(size_t)rr * DIMT4 + j];
                    sum.x += v.x; sum.y += v.y; sum.z += v.z; sum.w += v.w;
                    if (j < 16) {
                        sq.x = fmaf(v.x, v.x, sq.x); sq.y = fmaf(v.y, v.y, sq.y);
                        sq.z = fmaf(v.z, v.z, sq.z); sq.w = fmaf(v.w, v.w, sq.w);
                    }
                }
            }
        }
        // ---- block flush ----
        if (active) ssum[tid] = sum;
        if (active && j < 16) ssq[r_off * 16 + j] = sq;
        if (tid < 12) lstat[tid] = 0.f;
        __syncthreads();
        if (tid < 60) {
            float4 t0 = ssum[tid], t1 = ssum[60 + tid], t2 = ssum[120 + tid], t3 = ssum[180 + tid];
            float4 s4;
            s4.x = t0.x + t1.x + t2.x + t3.x;
            s4.y = t0.y + t1.y + t2.y + t3.y;
            s4.z = t0.z + t1.z + t2.z + t3.z;
            s4.w = t0.w + t1.w + t2.w + t3.w;
            if (tid < 16) {                          // l=0 columns 0..63
                atomicAdd(&lstat[0], s4.x + s4.y + s4.z + s4.w);
                float4 q0 = ssq[tid], q1 = ssq[16 + tid], q2 = ssq[32 + tid], q3 = ssq[48 + tid];
                float qs = (q0.x + q0.y + q0.z + q0.w) + (q1.x + q1.y + q1.z + q1.w)
                         + (q2.x + q2.y + q2.z + q2.w) + (q3.x + q3.y + q3.z + q3.w);
                atomicAdd(&lstat[1], qs);
            } else if (tid < 40) {                   // l=1, col = 4*tid+comp, d=(col-64)%3
                int base = 4 * tid - 64;
                atomicAdd(&lstat[2 + (base + 0) % 3], s4.x);
                atomicAdd(&lstat[2 + (base + 1) % 3], s4.y);
                atomicAdd(&lstat[2 + (base + 2) % 3], s4.z);
                atomicAdd(&lstat[2 + (base + 3) % 3], s4.w);
            } else {                                 // l=2, d=(col-160)%5
                int base = 4 * tid - 160;
                atomicAdd(&lstat[5 + (base + 0) % 5], s4.x);
                atomicAdd(&lstat[5 + (base + 1) % 5], s4.y);
                atomicAdd(&lstat[5 + (base + 2) % 5], s4.z);
                atomicAdd(&lstat[5 + (base + 3) % 5], s4.w);
            }
        }
        __syncthreads();
        if (tid < 11) atomicAdd(gstats + b_cur * 12 + 1 + tid, lstat[tid]);
        if (tid == 0) atomicAdd(gstats + b_cur * 12 + 0, (float)(r_end - r));
        __syncthreads();                             // protect lstat/ssum reuse
        r = r_end;
    }
}

// ---------------------------------------------------------------------------
// Kernel 2: finalize stats into per-(graph,col) affine table: y = x*A + B.
// ---------------------------------------------------------------------------
__global__ __launch_bounds__(256) void finalize_kernel(const float* __restrict__ gstats,
                                                       const float* __restrict__ weight,
                                                       const float* __restrict__ bias,
                                                       float* __restrict__ A,
                                                       float* __restrict__ B)
{
    int b = blockIdx.x;
    int c = threadIdx.x;
    if (c >= DIMT) return;
    const float* st = gstats + b * 12;
    float cnt   = fmaxf(st[0], 1.f);
    float mean0 = st[1] / (cnt * 64.f);
    float ex2   = st[2] / (cnt * 64.f);
    float norm  = fmaxf(ex2 - mean0 * mean0, 0.f);
    float scale = 1.f / (sqrtf(norm) + EPS);
    float a, bb;
    if (c < 64) {                       // l=0: normalize + weight + bias
        float w = weight[c];
        a  = scale * w;
        bb = bias[c] - mean0 * a;
    } else if (c < 160) {               // l=1: mean-subtract + weight
        int jj = c - 64;
        int d = jj % 3, m = jj / 3;
        float w = weight[64 + m];
        float mean = st[3 + d] / (cnt * 32.f);
        a = w; bb = -mean * w;
    } else {                            // l=2
        int jj = c - 160;
        int d = jj % 5, m = jj / 5;
        float w = weight[96 + m];
        float mean = st[6 + d] / (cnt * 16.f);
        a = w; bb = -mean * w;
    }
    A[b * DIMT + c] = a;
    B[b * DIMT + c] = bb;
}

// ---------------------------------------------------------------------------
// Kernel 3: apply, coalesced + register-cached A/B.
// Same (r_off, j) layout as stats. Per graph segment: load A/B float4 for
// (b_cur, j) ONCE into registers, then stream: out = x*a + b. Inner loop is
// pure load/fma/store with zero per-element index lookups.
// ---------------------------------------------------------------------------
__global__ __launch_bounds__(256) void apply_kernel(const float* __restrict__ x,
                                                    const int* __restrict__ batch,
                                                    const float* __restrict__ A,
                                                    const float* __restrict__ B,
                                                    float* __restrict__ out, int n)
{
    __shared__ int sbatch[ROWS];
    const int tid = threadIdx.x;
    const int r0 = blockIdx.x * ROWS;
    const int r1 = min(n, r0 + ROWS);
    if (r0 >= n) return;
    for (int i = tid; i < r1 - r0; i += 256) sbatch[i] = batch[r0 + i];
    __syncthreads();

    const bool active = tid < 240;
    const int  r_off  = tid / 60;
    const int  j      = tid - r_off * 60;
    const float4* x4  = (const float4*)x;
    float4*       o4  = (float4*)out;

    int r = r0;
    while (r < r1) {
        const int b_cur = sbatch[r - r0];
        int lo = r + 1, hi = r1;
        while (lo < hi) {
            int mid = (lo + hi) >> 1;
            if (sbatch[mid - r0] <= b_cur) lo = mid + 1; else hi = mid;
        }
        const int r_end = lo;

        if (active) {
            const float4 a  = ((const float4*)(A + b_cur * DIMT))[j];
            const float4 bb = ((const float4*)(B + b_cur * DIMT))[j];
            for (int rbase = r; rbase < r_end; rbase += 4) {
                int rr = rbase + r_off;
                if (rr < r_end) {
                    size_t idx = (size_t)rr * DIMT4 + j;
                    float4 v = x4[idx];
                    float4 o;
                    o.x = fmaf(v.x, a.x, bb.x);
                    o.y = fmaf(v.y, a.y, bb.y);
                    o.z = fmaf(v.z, a.z, bb.z);
                    o.w = fmaf(v.w, a.w, bb.w);
                    o4[idx] = o;
                }
            }
        }
        r = r_end;
    }
}

extern "C" void kernel_launch(void* const* d_in, const int* in_sizes, int n_in,
                              void* d_out, int out_size, void* d_ws, size_t ws_size,
                              hipStream_t stream) {
    const float* x      = (const float*)d_in[0];
    const int*   batch  = (const int*)d_in[1];
    const float* weight = (const float*)d_in[2];
    const float* bias   = (const float*)d_in[3];
    float*       out    = (float*)d_out;
    int n = in_sizes[1];                        // 200000 nodes

    float* gstats = (float*)d_ws;                                   // 64*12 floats
    float* A = (float*)((char*)d_ws + 4096);                        // 64*240 floats
    float* B = (float*)((char*)d_ws + 4096 + NGRAPH * DIMT * 4);    // 64*240 floats

    hipMemsetAsync(d_ws, 0, NGRAPH * 12 * sizeof(float), stream);

    int nblocks = (n + ROWS - 1) / ROWS;
    stats_kernel<<<nblocks, 256, 0, stream>>>(x, batch, gstats, n);
    finalize_kernel<<<NGRAPH, 256, 0, stream>>>(gstats, weight, bias, A, B);
    apply_kernel<<<nblocks, 256, 0, stream>>>(x, batch, A, B, out, n);
}